// Round 2
// baseline (539.055 us; speedup 1.0000x reference)
//
#include <hip/hip_runtime.h>
#include <math.h>

// TopKRouter: logits = rf @ gw^T, softmax, top-2, aux load-balance loss.
// rf: [16384, 4096] f32, gw: [64, 4096] f32.
// out (f32 flat): weights [0,32768) | indices-as-float [32768,65536) | aux [65536]

constexpr int B_ROWS = 16384;
constexpr int D_DIM  = 4096;
constexpr int E_EXP  = 64;
constexpr int BD     = 128;           // d-chunk per staging iteration
constexpr int TM     = 64;            // rows per block (= wavefront size, lane = row)
constexpr int NTHR   = 512;           // 8 waves; wave w owns experts 8w..8w+7
constexpr int NWAVE  = NTHR / 64;
constexpr int NCHUNK = D_DIM / BD;    // 32

__device__ __forceinline__ float wave_max64(float v) {
#pragma unroll
  for (int m = 32; m >= 1; m >>= 1) v = fmaxf(v, __shfl_xor(v, m, 64));
  return v;
}

__device__ __forceinline__ float wave_sum64(float v) {
#pragma unroll
  for (int m = 32; m >= 1; m >>= 1) v += __shfl_xor(v, m, 64);
  return v;
}

// argmax over 64 lanes; ties -> smaller index (matches jax.lax.top_k stability)
__device__ __forceinline__ void wave_argmax64(float v, int i, float& mv, int& mi) {
#pragma unroll
  for (int m = 32; m >= 1; m >>= 1) {
    float ov = __shfl_xor(v, m, 64);
    int   oi = __shfl_xor(i, m, 64);
    if (ov > v || (ov == v && oi < i)) { v = ov; i = oi; }
  }
  mv = v; mi = i;
}

// async global->LDS, 16B per lane. HW semantics: LDS dest = wave-uniform base
// + lane*16 (we arrange our per-lane dst to be exactly that); global src is
// per-lane (carries the pre-applied swizzle).
__device__ __forceinline__ void async_copy16(void* lds_dst, const void* g_src) {
  auto g = (const __attribute__((address_space(1))) char*)(g_src);
  auto l = (__attribute__((address_space(3))) char*)(lds_dst);
  __builtin_amdgcn_global_load_lds(g, l, 16, 0, 0);
}

__global__ __launch_bounds__(NTHR, 2) void router_fused(
    const float* __restrict__ rf, const float* __restrict__ gw,
    float* __restrict__ out, float* __restrict__ psum,
    unsigned int* __restrict__ cnt) {
  // double-buffered rf tile; LDS layout is LINEAR (required by global_load_lds),
  // the XOR bank-swizzle is pre-applied to the GLOBAL source column instead.
  __shared__ float buf[2][TM * BD];            // 2 x 32 KB
  __shared__ float lt[TM * (E_EXP + 1)];       // logits tile, +1 pad
  __shared__ unsigned int scnt[E_EXP];
  __shared__ float sP[NWAVE][E_EXP];

  const int t    = threadIdx.x;
  const int lane = t & 63;                     // = row within tile (compute phase)
  const int row0 = blockIdx.x * TM;
  const int e0   = (t >> 6) * 8;
  const int srz  = 4 * (lane & 15);            // read-side swizzle for my row

  if (t < E_EXP) scnt[t] = 0;

  // per-thread staging addresses: quad q = j*NTHR + t covers [r][dc];
  // LDS float index = q*4 (linear); global col = dc ^ swz(r).
  int goff[4], loff[4];
#pragma unroll
  for (int j = 0; j < 4; ++j) {
    int q  = j * NTHR + t;
    int r  = q >> 5;                 // 32 quads per row
    int dc = (q & 31) * 4;
    goff[j] = (row0 + r) * D_DIM + (dc ^ (4 * (r & 15)));
    loff[j] = q * 4;
  }

  float acc[8] = {0.f, 0.f, 0.f, 0.f, 0.f, 0.f, 0.f, 0.f};
  const int e0u = __builtin_amdgcn_readfirstlane(e0);
  const float* wb = gw + (size_t)e0u * D_DIM;  // wave-uniform base

  // prologue: stage chunk 0 into buf[0]
#pragma unroll
  for (int j = 0; j < 4; ++j) async_copy16(&buf[0][loff[j]], rf + goff[j]);

  for (int n = 0; n < NCHUNK; ++n) {
    const int cur = n & 1;
    if (n + 1 < NCHUNK) {
      // issue next chunk's loads into the other buffer (its last readers
      // finished before the closing barrier of iteration n-1)
#pragma unroll
      for (int j = 0; j < 4; ++j)
        async_copy16(&buf[cur ^ 1][loff[j]], rf + goff[j] + (n + 1) * BD);
      asm volatile("s_waitcnt vmcnt(4)" ::: "memory");  // chunk n resident (mine)
    } else {
      asm volatile("s_waitcnt vmcnt(0)" ::: "memory");
    }
    __builtin_amdgcn_s_barrier();                       // everyone's chunk n resident
    __builtin_amdgcn_sched_barrier(0);

    const float* bufc = &buf[cur][lane * BD];
    const float* wc   = wb + n * BD;
#pragma unroll 8
    for (int k = 0; k < BD / 4; ++k) {
      float4 a = *(const float4*)(bufc + ((4 * k) ^ srz));
      const float* wck = wc + 4 * k;
#pragma unroll
      for (int e = 0; e < 8; ++e) {
        float4 w4 = *(const float4*)(wck + (size_t)e * D_DIM);
        acc[e] = fmaf(a.x, w4.x, acc[e]);
        acc[e] = fmaf(a.y, w4.y, acc[e]);
        acc[e] = fmaf(a.z, w4.z, acc[e]);
        acc[e] = fmaf(a.w, w4.w, acc[e]);
      }
    }
    __builtin_amdgcn_sched_barrier(0);
    __builtin_amdgcn_s_barrier();                       // buf[cur] free for reuse
  }

  // scatter logits into padded LDS tile: lt[row][expert]
#pragma unroll
  for (int e = 0; e < 8; ++e) lt[lane * (E_EXP + 1) + e0 + e] = acc[e];
  __syncthreads();

  // stats phase: wave wv handles rows 8*wv..8*wv+7; lane = expert index
  const int wv = t >> 6;
  float Pacc = 0.f;
#pragma unroll
  for (int j = 0; j < 8; ++j) {
    const int r = wv * 8 + j;
    const float l = lt[r * (E_EXP + 1) + lane];
    const float m = wave_max64(l);
    const float p = __expf(l - m);
    const float s = wave_sum64(p);
    Pacc += p / s;
    float v1; int i1;
    wave_argmax64(l, lane, v1, i1);
    const float lm = (lane == i1) ? -INFINITY : l;
    float v2; int i2;
    wave_argmax64(lm, lane, v2, i2);
    if (lane == 0) {
      const float ex = expf(v2 - v1);   // v2 <= v1, stable
      const float w1 = 1.f / (1.f + ex);
      const float w2 = ex / (1.f + ex);
      const int row = row0 + r;
      out[row * 2 + 0] = w1;
      out[row * 2 + 1] = w2;
      out[2 * B_ROWS + row * 2 + 0] = (float)i1;
      out[2 * B_ROWS + row * 2 + 1] = (float)i2;
      atomicAdd(&scnt[i1], 1u);
      atomicAdd(&scnt[i2], 1u);
    }
  }
  sP[wv][lane] = Pacc;
  __syncthreads();
  if (t < E_EXP) {
    float tot = 0.f;
#pragma unroll
    for (int w = 0; w < NWAVE; ++w) tot += sP[w][t];
    atomicAdd(&psum[t], tot);
    atomicAdd(&cnt[t], scnt[t]);
  }
}

__global__ void aux_finalize(const float* __restrict__ psum,
                             const unsigned int* __restrict__ cnt,
                             float* __restrict__ out) {
  const int t = threadIdx.x;  // 64 threads
  const float f = (float)cnt[t] / (float)(B_ROWS * 2);
  const float P = psum[t] / (float)B_ROWS;
  float v = f * P;
  v = wave_sum64(v);
  if (t == 0) out[4 * B_ROWS] = (float)E_EXP * v;
}

extern "C" void kernel_launch(void* const* d_in, const int* in_sizes, int n_in,
                              void* d_out, int out_size, void* d_ws, size_t ws_size,
                              hipStream_t stream) {
  const float* rf = (const float*)d_in[0];
  const float* gw = (const float*)d_in[1];
  float* out = (float*)d_out;
  float* psum = (float*)d_ws;
  unsigned int* cnt = (unsigned int*)((char*)d_ws + 256);

  hipMemsetAsync(d_ws, 0, 512, stream);
  router_fused<<<B_ROWS / TM, NTHR, 0, stream>>>(rf, gw, out, psum, cnt);
  aux_finalize<<<1, 64, 0, stream>>>(psum, cnt, out);
}

// Round 3
// 361.921 us; speedup vs baseline: 1.4894x; 1.4894x over previous
//
#include <hip/hip_runtime.h>
#include <math.h>

// TopKRouter: logits = rf @ gw^T, softmax, top-2, aux load-balance loss.
// rf: [16384, 4096] f32, gw: [64, 4096] f32.
// out (f32 flat): weights [0,32768) | indices-as-float [32768,65536) | aux [65536]
//
// R2: split-D partial GEMM (grid 512 -> 2 blocks/CU) + separate epilogue kernel.
// ws layout: [0,256) psum f32[64] | [256,512) cnt u32[64] | [512, ...) partial
// logits [SPLITD][16384][64] f32.

constexpr int B_ROWS = 16384;
constexpr int D_DIM  = 4096;
constexpr int E_EXP  = 64;
constexpr int BD     = 128;           // d-chunk per staging iteration
constexpr int TM     = 64;            // rows per block (= wavefront, lane = row)
constexpr int NTHR   = 512;           // 8 waves; wave w owns experts 8w..8w+7

__device__ __forceinline__ float wave_max64(float v) {
#pragma unroll
  for (int m = 32; m >= 1; m >>= 1) v = fmaxf(v, __shfl_xor(v, m, 64));
  return v;
}

__device__ __forceinline__ float wave_sum64(float v) {
#pragma unroll
  for (int m = 32; m >= 1; m >>= 1) v += __shfl_xor(v, m, 64);
  return v;
}

// argmax over 64 lanes; ties -> smaller index (matches jax.lax.top_k)
__device__ __forceinline__ void wave_argmax64(float v, int i, float& mv, int& mi) {
#pragma unroll
  for (int m = 32; m >= 1; m >>= 1) {
    float ov = __shfl_xor(v, m, 64);
    int   oi = __shfl_xor(i, m, 64);
    if (ov > v || (ov == v && oi < i)) { v = ov; i = oi; }
  }
  mv = v; mi = i;
}

__device__ __forceinline__ void async_copy16(void* lds_dst, const void* g_src) {
  auto g = (const __attribute__((address_space(1))) char*)(g_src);
  auto l = (__attribute__((address_space(3))) char*)(lds_dst);
  __builtin_amdgcn_global_load_lds(g, l, 16, 0, 0);
}

template <int SPLITD>
__global__ __launch_bounds__(NTHR, 4) void gemm_partial(
    const float* __restrict__ rf, const float* __restrict__ gw,
    float* __restrict__ part) {
  constexpr int DSEG   = D_DIM / SPLITD;
  constexpr int NCHUNK = DSEG / BD;
  __shared__ float buf[2][TM * BD];            // 2 x 32 KB, linear (gload_lds)

  const int t    = threadIdx.x;
  const int lane = t & 63;                     // = row within tile
  const int rb   = blockIdx.x & 255;           // row-block
  const int sp   = blockIdx.x >> 8;            // d-split
  const int row0 = rb * TM;
  const int e0   = (t >> 6) * 8;
  const int srz  = 4 * (lane & 15);            // read-side bank swizzle

  const float* rfs = rf + sp * DSEG;           // this split's column window

  // staging addresses: quad q = j*NTHR + t -> [r][dc]; LDS linear, swizzle
  // pre-applied to the GLOBAL source column (global_load_lds writes linearly).
  int goff[4], loff[4];
#pragma unroll
  for (int j = 0; j < 4; ++j) {
    int q  = j * NTHR + t;
    int r  = q >> 5;
    int dc = (q & 31) * 4;
    goff[j] = (row0 + r) * D_DIM + (dc ^ (4 * (r & 15)));
    loff[j] = q * 4;
  }

  float acc[8] = {0.f, 0.f, 0.f, 0.f, 0.f, 0.f, 0.f, 0.f};
  const int e0u = __builtin_amdgcn_readfirstlane(e0);
  const float* wb = gw + (size_t)e0u * D_DIM + sp * DSEG;  // wave-uniform

#pragma unroll
  for (int j = 0; j < 4; ++j) async_copy16(&buf[0][loff[j]], rfs + goff[j]);

  for (int n = 0; n < NCHUNK; ++n) {
    const int cur = n & 1;
    if (n + 1 < NCHUNK) {
#pragma unroll
      for (int j = 0; j < 4; ++j)
        async_copy16(&buf[cur ^ 1][loff[j]], rfs + goff[j] + (n + 1) * BD);
      asm volatile("s_waitcnt vmcnt(4)" ::: "memory");  // my chunk-n loads done
    } else {
      asm volatile("s_waitcnt vmcnt(0)" ::: "memory");
    }
    __builtin_amdgcn_s_barrier();              // everyone's chunk n resident

    const float* bufc = &buf[cur][lane * BD];
    const float* wc   = wb + n * BD;
#pragma unroll 8
    for (int k = 0; k < BD / 4; ++k) {
      float4 a = *(const float4*)(bufc + ((4 * k) ^ srz));
      const float* wck = wc + 4 * k;
#pragma unroll
      for (int e = 0; e < 8; ++e) {
        float4 w4 = *(const float4*)(wck + (size_t)e * D_DIM);
        acc[e] = fmaf(a.x, w4.x, acc[e]);
        acc[e] = fmaf(a.y, w4.y, acc[e]);
        acc[e] = fmaf(a.z, w4.z, acc[e]);
        acc[e] = fmaf(a.w, w4.w, acc[e]);
      }
    }
    __builtin_amdgcn_s_barrier();              // buf[cur] free for reuse
  }

  // partial logits: [sp][row][expert]
  float* dst = part + ((size_t)sp * B_ROWS + row0 + lane) * E_EXP + e0;
  *(float4*)(dst + 0) = make_float4(acc[0], acc[1], acc[2], acc[3]);
  *(float4*)(dst + 4) = make_float4(acc[4], acc[5], acc[6], acc[7]);
}

template <int SPLITD>
__global__ __launch_bounds__(NTHR) void router_epilogue(
    const float* __restrict__ part, float* __restrict__ out,
    float* __restrict__ psum, unsigned int* __restrict__ cnt) {
  __shared__ unsigned int scnt[E_EXP];
  __shared__ float sP[NTHR / 64][E_EXP];

  const int t    = threadIdx.x;
  const int wv   = t >> 6;
  const int lane = t & 63;                     // = expert index here
  const int row0 = blockIdx.x * TM;

  if (t < E_EXP) scnt[t] = 0;
  __syncthreads();

  float Pacc = 0.f;
#pragma unroll
  for (int j = 0; j < 8; ++j) {
    const int row = row0 + wv * 8 + j;
    float l = part[(size_t)row * E_EXP + lane];
#pragma unroll
    for (int s = 1; s < SPLITD; ++s)
      l += part[((size_t)s * B_ROWS + row) * E_EXP + lane];

    const float m = wave_max64(l);
    const float p = __expf(l - m);
    const float ssum = wave_sum64(p);
    Pacc += p / ssum;

    float v1; int i1;
    wave_argmax64(l, lane, v1, i1);
    const float lm = (lane == i1) ? -INFINITY : l;
    float v2; int i2;
    wave_argmax64(lm, lane, v2, i2);
    if (lane == 0) {
      const float ex = expf(v2 - v1);          // v2 <= v1, stable
      const float w1 = 1.f / (1.f + ex);
      const float w2 = ex / (1.f + ex);
      out[row * 2 + 0] = w1;
      out[row * 2 + 1] = w2;
      out[2 * B_ROWS + row * 2 + 0] = (float)i1;
      out[2 * B_ROWS + row * 2 + 1] = (float)i2;
      atomicAdd(&scnt[i1], 1u);
      atomicAdd(&scnt[i2], 1u);
    }
  }
  sP[wv][lane] = Pacc;
  __syncthreads();
  if (t < E_EXP) {
    float tot = 0.f;
#pragma unroll
    for (int w = 0; w < NTHR / 64; ++w) tot += sP[w][t];
    atomicAdd(&psum[t], tot);
    atomicAdd(&cnt[t], scnt[t]);
  }
}

__global__ void aux_finalize(const float* __restrict__ psum,
                             const unsigned int* __restrict__ cnt,
                             float* __restrict__ out) {
  const int t = threadIdx.x;  // 64 threads
  const float f = (float)cnt[t] / (float)(B_ROWS * 2);
  const float P = psum[t] / (float)B_ROWS;
  float v = f * P;
  v = wave_sum64(v);
  if (t == 0) out[4 * B_ROWS] = (float)E_EXP * v;
}

extern "C" void kernel_launch(void* const* d_in, const int* in_sizes, int n_in,
                              void* d_out, int out_size, void* d_ws, size_t ws_size,
                              hipStream_t stream) {
  const float* rf = (const float*)d_in[0];
  const float* gw = (const float*)d_in[1];
  float* out  = (float*)d_out;
  float* psum = (float*)d_ws;
  unsigned int* cnt = (unsigned int*)((char*)d_ws + 256);
  float* part = (float*)((char*)d_ws + 512);

  hipMemsetAsync(d_ws, 0, 512, stream);

  const size_t per_split = (size_t)B_ROWS * E_EXP * sizeof(float);  // 4 MB
  if (ws_size >= 512 + 2 * per_split) {
    gemm_partial<2><<<512, NTHR, 0, stream>>>(rf, gw, part);
    router_epilogue<2><<<B_ROWS / TM, NTHR, 0, stream>>>(part, out, psum, cnt);
  } else {
    gemm_partial<1><<<256, NTHR, 0, stream>>>(rf, gw, part);
    router_epilogue<1><<<B_ROWS / TM, NTHR, 0, stream>>>(part, out, psum, cnt);
  }
  aux_finalize<<<1, 64, 0, stream>>>(psum, cnt, out);
}